// Round 1
// baseline (1019.980 us; speedup 1.0000x reference)
//
#include <hip/hip_runtime.h>
#include <math.h>

typedef _Float16 h2 __attribute__((ext_vector_type(2)));

#define NPOS 196
#define NH 4
#define KD 16
#define DV 64
#define DIM 256

static __device__ __forceinline__ float fdot2(h2 a, h2 b, float c) {
#if __has_builtin(__builtin_amdgcn_fdot2)
    return __builtin_amdgcn_fdot2(a, b, c, false);
#else
    return fmaf((float)a.x, (float)b.x, fmaf((float)a.y, (float)b.y, c));
#endif
}
static __device__ __forceinline__ h2 pk(float a, float b) {  // RTE pack
    h2 r; r.x = (_Float16)a; r.y = (_Float16)b; return r;
}
static __device__ __forceinline__ h2 pkz(float a, float b) { // RTZ pack (hot path)
#if __has_builtin(__builtin_amdgcn_cvt_pkrtz)
    return __builtin_bit_cast(h2, __builtin_amdgcn_cvt_pkrtz(a, b));
#else
    return pk(a, b);
#endif
}
union fhu { float f; h2 h; };
static __device__ __forceinline__ h2 as_h2(float f) { fhu u; u.f = f; return u.h; }
static __device__ __forceinline__ float as_f(h2 h) { fhu u; u.h = h; return u.f; }

// ---------------------------------------------------------------------------
// Kernel 0: pack proj_w -> wh2[c2][o] (half2 over c-pairs) and
//           qkv_w -> qw2[(i*96+o)][c2] (half2 over c-pairs).
// ---------------------------------------------------------------------------
__global__ void cga_prep(const float* __restrict__ pw, const float* __restrict__ qw,
                         h2* __restrict__ wh2, h2* __restrict__ qw2) {
    const int bid = blockIdx.x, t = threadIdx.x;
    if (bid < 128) {
        const int c2 = bid, o = t;
        wh2[c2 * DIM + o] = pk(pw[o * DIM + 2 * c2], pw[o * DIM + 2 * c2 + 1]);
    } else {
        const int idx = (bid - 128) * 256 + t;  // 0..12287 = 384*32
        const int c2 = idx & 31, oo = idx >> 5;
        qw2[idx] = pk(qw[oo * 64 + 2 * c2], qw[oo * 64 + 2 * c2 + 1]);
    }
}

// ---------------------------------------------------------------------------
// Kernel 1: fused cascaded attention. 512 threads/block (2 groups of 256),
// one block per batch. Group g = t>>8 splits every phase:
//   P1: g0 -> q (o 0..15) to ql fp32; g1 -> k (o 16..31) to kt fp16
//   P2: conv channels 8g..8g+7, post-gelu q exchanged fp16 via ql2
//   P3: v o8-blocks 4g..4g+3 -> vtp
//   P4: attention m-rows rm 7g..7g+6 (49 of 98 iters each), then a 2-round
//       fp32 LDS reduction (g0 owns d 0..31, g1 owns d 32..63).
// LDS map (63504 B total -> 2 blocks/CU = 16 waves/CU):
//   kt   [0, 6272)       half[196][16]
//   vtp  [6272, 31360)   98 rows x 256B, m-pair interleaved, XOR-swizzled
//                        (ql fp32[16][196] aliases [6272,18816))
//   bl   [31360, 32144)  fp32[196]
//   ql2  [32144, 38416)  h2[196][8] post-gelu q (denx fp32[2][196] aliases
//                        its head -- ql2 is dead by the time denx is written)
//   xbuf [38416, 63504)  fp32[196][32] partial/out exchange, 16B-XOR swizzle
// ---------------------------------------------------------------------------
__global__ __launch_bounds__(512, 4) void cga_main(
    const float* __restrict__ x,      // (512,256,196)
    const h2*    __restrict__ qw2,    // (4,96,32) half2
    const float* __restrict__ qkv_s,  // (4,96)
    const float* __restrict__ qkv_b,  // (4,96)
    const float* __restrict__ dw_w,   // (4,16,25)
    const float* __restrict__ dw_s,   // (4,16)
    const float* __restrict__ dw_b,   // (4,16)
    const float* __restrict__ ab,     // (4,196)
    h2* __restrict__ catI)            // (512,128,196) half2 over c-pairs
{
    __shared__ __align__(16) char smem[63504];
    char*   vtpB = smem + 6272;
    float*  ql   = (float*)(smem + 6272);
    float*  bl   = (float*)(smem + 31360);
    char*   ql2B = smem + 32144;
    float*  denx = (float*)(smem + 32144);   // aliases ql2 head (dead by use)
    float4* xb4  = (float4*)(smem + 38416);

    const int t  = threadIdx.x;
    const int g  = t >> 8;            // wave-uniform group id
    const int tl = t & 255;
    const int b  = blockIdx.x;
    const bool act = tl < NPOS;
    const int n  = act ? tl : (NPOS - 1);
    const int rn = n / 14;
    const int cn = n - rn * 14;

    const float* xb = x + (size_t)b * (DIM * NPOS);

    h2 feat2[32];
#pragma unroll
    for (int e = 0; e < 32; ++e)
        feat2[e] = pk(xb[(2 * e) * NPOS + n], xb[(2 * e + 1) * NPOS + n]);

#pragma unroll 1
    for (int i = 0; i < NH; ++i) {
        const h2* w2    = qw2 + i * (96 * 32);
        const float* sc = qkv_s + i * 96;
        const float* bi = qkv_b + i * 96;

        if (t < NPOS) bl[t] = ab[i * NPOS + t] - 4.0f;  // softmax-invariant shift

        // ---- P1: g0: q -> ql fp32 ; g1: k -> kt fp16 ----------------------
#pragma unroll 1
        for (int o8g = 0; o8g < 2; ++o8g) {
            const int o8 = 2 * g + o8g;
            const int ob = o8 * 8;
            const h2* w0 = w2 + ob * 32;
            float s[8];
#pragma unroll
            for (int j = 0; j < 8; ++j) s[j] = 0.f;
#pragma unroll
            for (int c2 = 0; c2 < 32; ++c2) {
                h2 f = feat2[c2];
#pragma unroll
                for (int j = 0; j < 8; ++j) s[j] = fdot2(f, w0[j * 32 + c2], s[j]);
            }
#pragma unroll
            for (int j = 0; j < 8; ++j) s[j] = fmaf(s[j], sc[ob + j], bi[ob + j]);
            if (act) {
                if (g == 0) {
#pragma unroll
                    for (int j = 0; j < 8; ++j) ql[(ob + j) * NPOS + n] = s[j];
                } else {
                    float4 kw;
                    kw.x = as_f(pk(s[0], s[1]));
                    kw.y = as_f(pk(s[2], s[3]));
                    kw.z = as_f(pk(s[4], s[5]));
                    kw.w = as_f(pk(s[6], s[7]));
                    *(float4*)(smem + n * 32 + (o8 - 2) * 16) = kw;
                }
            }
        }
        __syncthreads();                                           // A

        // ---- P2: depthwise conv + affine + gelu + residual (8 ch/group) ---
        h2 q2h[8];
        {
            const int ch0 = 8 * g;
            const float* dww = dw_w + i * (KD * 25) + ch0 * 25;
            const float* dws = dw_s + i * KD + ch0;
            const float* dwb = dw_b + i * KD + ch0;
            float q2[8];
#pragma unroll
            for (int ch = 0; ch < 8; ++ch) {
                float s = 0.f;
#pragma unroll
                for (int kr = 0; kr < 5; ++kr) {
                    int rr = rn + kr - 2;
                    bool rok = (unsigned)rr < 14u;
#pragma unroll
                    for (int kc = 0; kc < 5; ++kc) {
                        int cc = cn + kc - 2;
                        bool ok = rok && ((unsigned)cc < 14u);
                        int idx = ok ? (rr * 14 + cc) : n;
                        float qv = ql[(ch0 + ch) * NPOS + idx];
                        qv = ok ? qv : 0.f;
                        s = fmaf(qv, dww[ch * 25 + kr * 5 + kc], s);
                    }
                }
                float dv = fmaf(s, dws[ch], dwb[ch]);
                float gg = 0.5f * dv * (1.f + erff(dv * 0.70710678118654752f));
                q2[ch] = gg + ql[(ch0 + ch) * NPOS + n];
            }
            if (act) {
                float4 qh;
                qh.x = as_f(pk(q2[0], q2[1]));
                qh.y = as_f(pk(q2[2], q2[3]));
                qh.z = as_f(pk(q2[4], q2[5]));
                qh.w = as_f(pk(q2[6], q2[7]));
                *(float4*)(ql2B + n * 32 + g * 16) = qh;
            }
        }
        __syncthreads();                                           // B
        {
            const float4* qr = (const float4*)(ql2B + n * 32);
            float4 qa = qr[0], qb2 = qr[1];
            q2h[0] = as_h2(qa.x);  q2h[1] = as_h2(qa.y);
            q2h[2] = as_h2(qa.z);  q2h[3] = as_h2(qa.w);
            q2h[4] = as_h2(qb2.x); q2h[5] = as_h2(qb2.y);
            q2h[6] = as_h2(qb2.z); q2h[7] = as_h2(qb2.w);
        }

        // ---- P3: v -> vtp m-pair-interleaved fp16 (4 blocks/group) --------
#pragma unroll 1
        for (int j8 = 0; j8 < 4; ++j8) {
            const int o8v = 4 * g + j8;
            const int ob = 32 + o8v * 8;
            const h2* w0 = w2 + ob * 32;
            float s[8];
#pragma unroll
            for (int j = 0; j < 8; ++j) s[j] = 0.f;
#pragma unroll
            for (int c2 = 0; c2 < 32; ++c2) {
                h2 f = feat2[c2];
#pragma unroll
                for (int j = 0; j < 8; ++j) s[j] = fdot2(f, w0[j * 32 + c2], s[j]);
            }
#pragma unroll
            for (int j = 0; j < 8; ++j) s[j] = fmaf(s[j], sc[ob + j], bi[ob + j]);

            float sp[8];
#pragma unroll
            for (int j = 0; j < 8; ++j) sp[j] = __shfl_xor(s[j], 1, 64);
            const int par = t & 1;
            float4 vw;
            if (par == 0) {  // lane holds m0: (own, partner)
                vw.x = as_f(pk(s[0], sp[0])); vw.y = as_f(pk(s[1], sp[1]));
                vw.z = as_f(pk(s[2], sp[2])); vw.w = as_f(pk(s[3], sp[3]));
            } else {         // lane holds m1: (partner, own)
                vw.x = as_f(pk(sp[4], s[4])); vw.y = as_f(pk(sp[5], s[5]));
                vw.z = as_f(pk(sp[6], s[6])); vw.w = as_f(pk(sp[7], s[7]));
            }
            if (act) {
                const int mp = n >> 1;
                const int gk = 2 * o8v + par;  // 16B chunk id 0..15
                *(float4*)(vtpB + mp * 256 + ((gk ^ (mp & 15)) << 4)) = vw;
            }
        }
        __syncthreads();                                           // C

        // ---- P4: attention row n, m-rows rm = 7g .. 7g+6 ------------------
        float acc[DV];
#pragma unroll
        for (int d = 0; d < DV; ++d) acc[d] = 0.f;
        float den = 0.f;

#pragma unroll 1
        for (int rm = 7 * g; rm < 7 * g + 7; ++rm) {
            const int drr = (rn >= rm ? rn - rm : rm - rn) * 14;
            const int mrow = rm * 14;
            for (int cmp = 0; cmp < 7; ++cmp) {
                const int m0 = mrow + 2 * cmp;
                const int mp = m0 >> 1;
                const float4* kr0 = (const float4*)(smem + m0 * 32);
                float4 ka = kr0[0], kb = kr0[1];
                const float4* kr1 = (const float4*)(smem + m0 * 32 + 32);
                float4 kc = kr1[0], kd = kr1[1];

                float s0a = fdot2(q2h[0], as_h2(ka.x), 0.f);
                s0a = fdot2(q2h[1], as_h2(ka.y), s0a);
                s0a = fdot2(q2h[2], as_h2(ka.z), s0a);
                s0a = fdot2(q2h[3], as_h2(ka.w), s0a);
                float s0b = fdot2(q2h[4], as_h2(kb.x), 0.f);
                s0b = fdot2(q2h[5], as_h2(kb.y), s0b);
                s0b = fdot2(q2h[6], as_h2(kb.z), s0b);
                s0b = fdot2(q2h[7], as_h2(kb.w), s0b);
                float s1a = fdot2(q2h[0], as_h2(kc.x), 0.f);
                s1a = fdot2(q2h[1], as_h2(kc.y), s1a);
                s1a = fdot2(q2h[2], as_h2(kc.z), s1a);
                s1a = fdot2(q2h[3], as_h2(kc.w), s1a);
                float s1b = fdot2(q2h[4], as_h2(kd.x), 0.f);
                s1b = fdot2(q2h[5], as_h2(kd.y), s1b);
                s1b = fdot2(q2h[6], as_h2(kd.z), s1b);
                s1b = fdot2(q2h[7], as_h2(kd.w), s1b);

                const int cm0 = 2 * cmp, cm1 = cm0 + 1;
                const int dc0 = cn >= cm0 ? cn - cm0 : cm0 - cn;
                const int dc1 = cn >= cm1 ? cn - cm1 : cm1 - cn;
                float p0 = __expf(fmaf(s0a + s0b, 0.25f, bl[drr + dc0]));
                float p1 = __expf(fmaf(s1a + s1b, 0.25f, bl[drr + dc1]));
                den += p0 + p1;
                h2 ph = pkz(p0, p1);

                const char* vrow = vtpB + mp * 256;
                const int sw = mp & 15;
#pragma unroll
                for (int gq = 0; gq < 16; ++gq) {
                    float4 vv = *(const float4*)(vrow + ((gq ^ sw) << 4));
                    acc[4 * gq + 0] = fdot2(ph, as_h2(vv.x), acc[4 * gq + 0]);
                    acc[4 * gq + 1] = fdot2(ph, as_h2(vv.y), acc[4 * gq + 1]);
                    acc[4 * gq + 2] = fdot2(ph, as_h2(vv.z), acc[4 * gq + 2]);
                    acc[4 * gq + 3] = fdot2(ph, as_h2(vv.w), acc[4 * gq + 3]);
                }
            }
        }

        // ---- reduction + epilogue (2 rounds of 32 channels) ---------------
        // R0: publish den partials; g1 publishes acc[0..31] partial.
        if (act) {
            denx[g * NPOS + n] = den;
            if (g == 1) {
                float4* xr = xb4 + n * 8;
#pragma unroll
                for (int k2 = 0; k2 < 8; ++k2) {
                    float4 w;
                    w.x = acc[4 * k2];     w.y = acc[4 * k2 + 1];
                    w.z = acc[4 * k2 + 2]; w.w = acc[4 * k2 + 3];
                    xr[k2 ^ (n & 7)] = w;
                }
            }
        }
        __syncthreads();                                           // D

        const float inv = 1.f / (denx[n] + denx[NPOS + n]);
        h2* cb = catI + ((size_t)b * 128 + i * 32) * NPOS;
        const float* xn = xb + (size_t)(i + 1) * (DV * NPOS);
        const bool more = (i < NH - 1);

        // R1: g0 reduces d 0..31, writes catI lo, publishes out lo.
        if (g == 0) {
            float4* xr = xb4 + n * 8;
            float ov[32];
#pragma unroll
            for (int k2 = 0; k2 < 8; ++k2) {
                float4 p = xr[k2 ^ (n & 7)];
                ov[4 * k2]     = (acc[4 * k2]     + p.x) * inv;
                ov[4 * k2 + 1] = (acc[4 * k2 + 1] + p.y) * inv;
                ov[4 * k2 + 2] = (acc[4 * k2 + 2] + p.z) * inv;
                ov[4 * k2 + 3] = (acc[4 * k2 + 3] + p.w) * inv;
            }
            if (act) {
#pragma unroll
                for (int e = 0; e < 16; ++e)
                    cb[e * NPOS + n] = pk(fmaxf(ov[2 * e], 0.f),
                                          fmaxf(ov[2 * e + 1], 0.f));
                if (more) {
#pragma unroll
                    for (int k2 = 0; k2 < 8; ++k2) {
                        float4 w;
                        w.x = ov[4 * k2];     w.y = ov[4 * k2 + 1];
                        w.z = ov[4 * k2 + 2]; w.w = ov[4 * k2 + 3];
                        xr[k2 ^ (n & 7)] = w;
                    }
                }
            }
            if (more) {
#pragma unroll
                for (int e = 0; e < 16; ++e)
                    feat2[e] = pk(ov[2 * e]     + xn[(2 * e) * NPOS + n],
                                  ov[2 * e + 1] + xn[(2 * e + 1) * NPOS + n]);
            }
        }
        __syncthreads();                                           // E

        // R2: g1 reads out lo -> feat2 lo.
        if (g == 1 && more) {
            const float4* xr = xb4 + n * 8;
#pragma unroll
            for (int k2 = 0; k2 < 8; ++k2) {
                float4 p = xr[k2 ^ (n & 7)];
                feat2[2 * k2]     = pk(p.x + xn[(4 * k2) * NPOS + n],
                                       p.y + xn[(4 * k2 + 1) * NPOS + n]);
                feat2[2 * k2 + 1] = pk(p.z + xn[(4 * k2 + 2) * NPOS + n],
                                       p.w + xn[(4 * k2 + 3) * NPOS + n]);
            }
        }
        __syncthreads();                                           // F

        // R3: g0 publishes acc[32..63] partial.
        if (g == 0 && act) {
            float4* xr = xb4 + n * 8;
#pragma unroll
            for (int k2 = 0; k2 < 8; ++k2) {
                float4 w;
                w.x = acc[32 + 4 * k2]; w.y = acc[33 + 4 * k2];
                w.z = acc[34 + 4 * k2]; w.w = acc[35 + 4 * k2];
                xr[k2 ^ (n & 7)] = w;
            }
        }
        __syncthreads();                                           // G

        // R4: g1 reduces d 32..63, writes catI hi, publishes out hi.
        if (g == 1) {
            float4* xr = xb4 + n * 8;
            float ov[32];
#pragma unroll
            for (int k2 = 0; k2 < 8; ++k2) {
                float4 p = xr[k2 ^ (n & 7)];
                ov[4 * k2]     = (acc[32 + 4 * k2] + p.x) * inv;
                ov[4 * k2 + 1] = (acc[33 + 4 * k2] + p.y) * inv;
                ov[4 * k2 + 2] = (acc[34 + 4 * k2] + p.z) * inv;
                ov[4 * k2 + 3] = (acc[35 + 4 * k2] + p.w) * inv;
            }
            if (act) {
#pragma unroll
                for (int e = 0; e < 16; ++e)
                    cb[(16 + e) * NPOS + n] = pk(fmaxf(ov[2 * e], 0.f),
                                                 fmaxf(ov[2 * e + 1], 0.f));
                if (more) {
#pragma unroll
                    for (int k2 = 0; k2 < 8; ++k2) {
                        float4 w;
                        w.x = ov[4 * k2];     w.y = ov[4 * k2 + 1];
                        w.z = ov[4 * k2 + 2]; w.w = ov[4 * k2 + 3];
                        xr[k2 ^ (n & 7)] = w;
                    }
                }
            }
            if (more) {
#pragma unroll
                for (int e = 0; e < 16; ++e)
                    feat2[16 + e] = pk(ov[2 * e]     + xn[(32 + 2 * e) * NPOS + n],
                                       ov[2 * e + 1] + xn[(33 + 2 * e) * NPOS + n]);
            }
        }
        __syncthreads();                                           // H

        // R5: g0 reads out hi -> feat2 hi. (Barrier A of the next head orders
        // these reads against the next R0 xbuf writes.)
        if (g == 0 && more) {
            const float4* xr = xb4 + n * 8;
#pragma unroll
            for (int k2 = 0; k2 < 8; ++k2) {
                float4 p = xr[k2 ^ (n & 7)];
                feat2[16 + 2 * k2]     = pk(p.x + xn[(32 + 4 * k2) * NPOS + n],
                                            p.y + xn[(33 + 4 * k2) * NPOS + n]);
                feat2[16 + 2 * k2 + 1] = pk(p.z + xn[(34 + 4 * k2) * NPOS + n],
                                            p.w + xn[(35 + 4 * k2) * NPOS + n]);
            }
        }
    }
}

// ---------------------------------------------------------------------------
// Kernel 2: proj GEMM via fdot2. Block = (b, 28-col chunk). thread = out chan.
// ---------------------------------------------------------------------------
__global__ __launch_bounds__(256, 4) void cga_proj(
    const h2* __restrict__ catI, const h2* __restrict__ wh2,
    const float* __restrict__ ps, const float* __restrict__ pb,
    float* __restrict__ out)
{
    __shared__ __align__(16) h2 cl[128 * 28];  // 14336 B
    const int t = threadIdx.x;
    const int b = blockIdx.x / 7;
    const int nc = blockIdx.x - b * 7;
    const int n0 = nc * 28;

    const h2* cb = catI + (size_t)b * (128 * NPOS) + n0;
    for (int idx = t; idx < 128 * 7; idx += 256) {
        int c2 = idx / 7;
        int j4 = idx - c2 * 7;
        *(float4*)&cl[c2 * 28 + j4 * 4] = *(const float4*)&cb[c2 * NPOS + j4 * 4];
    }
    __syncthreads();

    float acc[28];
#pragma unroll
    for (int j = 0; j < 28; ++j) acc[j] = 0.f;

    const h2* wcol = wh2 + t;
    h2 wv[8];
#pragma unroll
    for (int j = 0; j < 8; ++j) wv[j] = wcol[j * DIM];

#pragma unroll 1
    for (int c8 = 0; c8 < 16; ++c8) {
        h2 wn[8];
#pragma unroll
        for (int j = 0; j < 8; ++j)
            wn[j] = wcol[(((c8 * 8) + 8 + j) & 127) * DIM];
#pragma unroll
        for (int j = 0; j < 8; ++j) {
            h2 w = wv[j];
            const float4* cf = (const float4*)&cl[(c8 * 8 + j) * 28];
#pragma unroll
            for (int j4 = 0; j4 < 7; ++j4) {
                float4 cv = cf[j4];
                acc[j4 * 4 + 0] = fdot2(w, as_h2(cv.x), acc[j4 * 4 + 0]);
                acc[j4 * 4 + 1] = fdot2(w, as_h2(cv.y), acc[j4 * 4 + 1]);
                acc[j4 * 4 + 2] = fdot2(w, as_h2(cv.z), acc[j4 * 4 + 2]);
                acc[j4 * 4 + 3] = fdot2(w, as_h2(cv.w), acc[j4 * 4 + 3]);
            }
        }
#pragma unroll
        for (int j = 0; j < 8; ++j) wv[j] = wn[j];
    }

    float s = ps[t], bb = pb[t];
    float* ob = out + ((size_t)b * DIM + t) * NPOS + n0;
#pragma unroll
    for (int j = 0; j < 28; ++j) ob[j] = fmaf(acc[j], s, bb);
}

extern "C" void kernel_launch(void* const* d_in, const int* in_sizes, int n_in,
                              void* d_out, int out_size, void* d_ws, size_t ws_size,
                              hipStream_t stream) {
    const float* x      = (const float*)d_in[0];
    const float* qkv_w  = (const float*)d_in[1];
    const float* qkv_s  = (const float*)d_in[2];
    const float* qkv_b  = (const float*)d_in[3];
    const float* dw_w   = (const float*)d_in[4];
    const float* dw_s   = (const float*)d_in[5];
    const float* dw_b   = (const float*)d_in[6];
    const float* proj_w = (const float*)d_in[7];
    const float* proj_s = (const float*)d_in[8];
    const float* proj_b = (const float*)d_in[9];
    const float* ab     = (const float*)d_in[10];
    float* out = (float*)d_out;

    h2* wh2  = (h2*)d_ws;                          // 32768 h2 = 131072 B
    h2* qw2  = (h2*)((char*)d_ws + 131072);        // 12288 h2 = 49152 B
    h2* catI = (h2*)((char*)d_ws + 180224);        // 512*128*196 h2 = 51.4 MB

    cga_prep<<<176, 256, 0, stream>>>(proj_w, qkv_w, wh2, qw2);
    cga_main<<<512, 512, 0, stream>>>(x, qw2, qkv_s, qkv_b,
                                      dw_w, dw_s, dw_b, ab, catI);
    cga_proj<<<512 * 7, 256, 0, stream>>>(catI, wh2, proj_s, proj_b, out);
}

// Round 3
// 509.759 us; speedup vs baseline: 2.0009x; 2.0009x over previous
//
#include <hip/hip_runtime.h>
#include <math.h>

typedef _Float16 h2 __attribute__((ext_vector_type(2)));
typedef _Float16 f16x4 __attribute__((ext_vector_type(4)));
typedef float f32x4 __attribute__((ext_vector_type(4)));

#define NPOS 196
#define NH 4
#define KD 16
#define DV 64
#define DIM 256

// K=16 f16 MFMA, carried forward on gfx950. Unconditional define: hipcc
// accepts amdgcn builtins in device code in both host+device passes.
#define MFMA16(A,B,C) __builtin_amdgcn_mfma_f32_16x16x16f16((A),(B),(C),0,0,0)

static __device__ __forceinline__ float fdot2(h2 a, h2 b, float c) {
#if __has_builtin(__builtin_amdgcn_fdot2)
    return __builtin_amdgcn_fdot2(a, b, c, false);
#else
    return fmaf((float)a.x, (float)b.x, fmaf((float)a.y, (float)b.y, c));
#endif
}
static __device__ __forceinline__ h2 pk(float a, float b) {  // RTE pack
    h2 r; r.x = (_Float16)a; r.y = (_Float16)b; return r;
}
static __device__ __forceinline__ h2 pkz(float a, float b) { // RTZ pack (hot path)
#if __has_builtin(__builtin_amdgcn_cvt_pkrtz)
    return __builtin_bit_cast(h2, __builtin_amdgcn_cvt_pkrtz(a, b));
#else
    return pk(a, b);
#endif
}
union fhu { float f; h2 h; };
static __device__ __forceinline__ h2 as_h2(float f) { fhu u; u.f = f; return u.h; }
static __device__ __forceinline__ float as_f(h2 h) { fhu u; u.h = h; return u.f; }
static __device__ __forceinline__ f16x4 mk4(h2 a, h2 b) {
    union { f16x4 v; h2 h[2]; } u; u.h[0] = a; u.h[1] = b; return u.v;
}

// ---------------------------------------------------------------------------
// Kernel 0: pack proj_w -> wh2[c2][o] (half2 over c-pairs) and
//           qkv_w -> qw2[(i*96+o)][c2] (half2 over c-pairs).
// ---------------------------------------------------------------------------
__global__ void cga_prep(const float* __restrict__ pw, const float* __restrict__ qw,
                         h2* __restrict__ wh2, h2* __restrict__ qw2) {
    const int bid = blockIdx.x, t = threadIdx.x;
    if (bid < 128) {
        const int c2 = bid, o = t;
        wh2[c2 * DIM + o] = pk(pw[o * DIM + 2 * c2], pw[o * DIM + 2 * c2 + 1]);
    } else {
        const int idx = (bid - 128) * 256 + t;  // 0..12287 = 384*32
        const int c2 = idx & 31, oo = idx >> 5;
        qw2[idx] = pk(qw[oo * 64 + 2 * c2], qw[oo * 64 + 2 * c2 + 1]);
    }
}

// ---------------------------------------------------------------------------
// Kernel 1: fused cascaded attention, MFMA 16x16x16 f16 for QKV / QK^T / AV.
// 256 threads (4 waves) per block, one block per batch.
// Tiles of 16 over n (13 tiles, padded 196->208); wave w owns n-tiles
// {w, w+4, w+8, w+12}.
// Fragment facts used (gfx950 v_mfma_f32_16x16x16_f16):
//   A[m][k]: lane holds m = l%16,     k = (l/16)*4 + j
//   B[k][n]: lane holds n = l%16,     k = (l/16)*4 + j
//   D[m][n]: lane holds n = l%16,     m = (l/16)*4 + j
// Key identities exploited:
//   * K-projection D-frag (Y rows 16..31, "n-tile"=mt) IS the A-frag of
//     S^T = K^T Q' for m-tile mt -> K lives in 26 VGPRs, never in LDS.
//   * S^T D-frag (n = l%16 fixed, m in reg idx) IS the B-frag (P^T) that
//     AV (O = V P^T) needs -> P never round-trips through LDS.
// LDS map (65104 B, 2 blocks/CU):
//   xf [0,28288)      halves [208][68]  feat (fp16), rows 196..207 zero
//   vt [28288,55936)  halves [64][216]  V [d][m]; cols 196..207 zeroed/head
//      ql (alias)     fp32 [16][196]    pre-conv q (dead before vt written)
//   qn [55936,64256)  halves [208][20]  post-gelu q' [n][k], pad rows zero
//   bl [64256,65104)  fp32 [212]        attention bias row (shifted -4)
// ---------------------------------------------------------------------------
__global__ __launch_bounds__(256, 2) void cga_main(
    const float* __restrict__ x,      // (512,256,196)
    const h2*    __restrict__ qw2,    // (4,96,32) half2 = rows of 64 halves
    const float* __restrict__ qkv_s,  // (4,96)
    const float* __restrict__ qkv_b,  // (4,96)
    const float* __restrict__ dw_w,   // (4,16,25)
    const float* __restrict__ dw_s,   // (4,16)
    const float* __restrict__ dw_b,   // (4,16)
    const float* __restrict__ ab,     // (4,196)
    h2* __restrict__ catI)            // (512,128,196) half2 over c-pairs
{
    __shared__ __align__(16) char smem[65104];
    _Float16* xf = (_Float16*)smem;             // pitch 68 halves (136 B)
    _Float16* vt = (_Float16*)(smem + 28288);   // pitch 216 halves (432 B)
    float*    ql = (float*)(smem + 28288);      // pitch 196 f32 (alias vt)
    _Float16* qn = (_Float16*)(smem + 55936);   // pitch 20 halves (40 B)
    float*    bl = (float*)(smem + 64256);

    const int t  = threadIdx.x;
    const int l  = t & 63;
    const int w  = t >> 6;       // wave id 0..3
    const int lr = l & 15;       // lane % 16
    const int lq = l >> 4;       // lane / 16 (quarter)
    const int b  = blockIdx.x;
    const bool act = t < NPOS;
    const int n  = act ? t : (NPOS - 1);
    const int rn = n / 14;
    const int cn = n - rn * 14;

    const float* xb = x + (size_t)b * (DIM * NPOS);

    // ---- init: xf <- x (head-0 feat), zero pads ---------------------------
    if (act) {
#pragma unroll
        for (int c2 = 0; c2 < 32; ++c2)
            *(h2*)(xf + t * 68 + 2 * c2) =
                pk(xb[(2 * c2) * NPOS + t], xb[(2 * c2 + 1) * NPOS + t]);
    }
    if (t < 204) {  // xf rows 196..207: 12 rows * 68 halves = 204 * 4 halves
        int row = 196 + t / 17, off = t - (t / 17) * 17;
        *(float2*)(xf + row * 68 + off * 4) = make_float2(0.f, 0.f);
    }
    if (t < 60) {   // qn rows 196..207: 12 rows * 20 halves = 60 * 4 halves
        int row = 196 + t / 5, off = t - (t / 5) * 5;
        *(float2*)(qn + row * 20 + off * 4) = make_float2(0.f, 0.f);
    }
    __syncthreads();

    const f32x4 fz = {0.f, 0.f, 0.f, 0.f};

#pragma unroll 1
    for (int i = 0; i < NH; ++i) {
        const _Float16* wq = (const _Float16*)qw2 + (size_t)i * (96 * 64);
        const float* sc = qkv_s + i * 96;
        const float* bi = qkv_b + i * 96;

        if (t < NPOS)      bl[t] = ab[i * NPOS + t] - 4.0f;  // softmax-invariant
        else if (t < 212)  bl[t] = 0.f;

        // ---- p1a: q projection (o 0..15) -> ql fp32 -----------------------
        {
            f16x4 aq0 = *(const f16x4*)(wq + lr * 64 +  0 + lq * 4);
            f16x4 aq1 = *(const f16x4*)(wq + lr * 64 + 16 + lq * 4);
            f16x4 aq2 = *(const f16x4*)(wq + lr * 64 + 32 + lq * 4);
            f16x4 aq3 = *(const f16x4*)(wq + lr * 64 + 48 + lq * 4);
            float s0 = sc[lq * 4 + 0], s1 = sc[lq * 4 + 1];
            float s2 = sc[lq * 4 + 2], s3 = sc[lq * 4 + 3];
            float b0 = bi[lq * 4 + 0], b1 = bi[lq * 4 + 1];
            float b2 = bi[lq * 4 + 2], b3 = bi[lq * 4 + 3];
#pragma unroll 1
            for (int nt = w; nt < 13; nt += 4) {
                const _Float16* xr = xf + (nt * 16 + lr) * 68;
                f32x4 acc = fz;
                acc = MFMA16(aq0, *(const f16x4*)(xr +  0 + lq * 4), acc);
                acc = MFMA16(aq1, *(const f16x4*)(xr + 16 + lq * 4), acc);
                acc = MFMA16(aq2, *(const f16x4*)(xr + 32 + lq * 4), acc);
                acc = MFMA16(aq3, *(const f16x4*)(xr + 48 + lq * 4), acc);
                int nn = nt * 16 + lr;
                if (nn < NPOS) {
                    ql[(lq * 4 + 0) * NPOS + nn] = fmaf(acc[0], s0, b0);
                    ql[(lq * 4 + 1) * NPOS + nn] = fmaf(acc[1], s1, b1);
                    ql[(lq * 4 + 2) * NPOS + nn] = fmaf(acc[2], s2, b2);
                    ql[(lq * 4 + 3) * NPOS + nn] = fmaf(acc[3], s3, b3);
                }
            }
        }
        __syncthreads();  // B1: ql ready

        // ---- p2: 5x5 depthwise conv + affine + gelu + residual -> qn ------
        {
            const float* dww = dw_w + i * (KD * 25);
            const float* dws = dw_s + i * KD;
            const float* dwb = dw_b + i * KD;
            float q2[KD];
#pragma unroll
            for (int ch = 0; ch < KD; ++ch) {
                float s = 0.f;
#pragma unroll
                for (int kr = 0; kr < 5; ++kr) {
                    int rr = rn + kr - 2;
                    bool rok = (unsigned)rr < 14u;
#pragma unroll
                    for (int kc = 0; kc < 5; ++kc) {
                        int cc = cn + kc - 2;
                        bool ok = rok && ((unsigned)cc < 14u);
                        int idx = ok ? (rr * 14 + cc) : n;
                        float qv = ql[ch * NPOS + idx];
                        qv = ok ? qv : 0.f;
                        s = fmaf(qv, dww[ch * 25 + kr * 5 + kc], s);
                    }
                }
                float dv = fmaf(s, dws[ch], dwb[ch]);
                float g = 0.5f * dv * (1.f + erff(dv * 0.70710678118654752f));
                q2[ch] = g + ql[ch * NPOS + n];
            }
            if (act) {
#pragma unroll
                for (int e = 0; e < 8; ++e)
                    *(h2*)(qn + n * 20 + 2 * e) = pk(q2[2 * e], q2[2 * e + 1]);
            }
        }
        __syncthreads();  // B2: conv done reading ql; vt may overwrite it

        // ---- p1b: K projection -> kf regs (redundant per wave);
        //           V projection -> vt [d][m] ------------------------------
        f16x4 kf[13];
        {
            f16x4 ak0 = *(const f16x4*)(wq + (16 + lr) * 64 +  0 + lq * 4);
            f16x4 ak1 = *(const f16x4*)(wq + (16 + lr) * 64 + 16 + lq * 4);
            f16x4 ak2 = *(const f16x4*)(wq + (16 + lr) * 64 + 32 + lq * 4);
            f16x4 ak3 = *(const f16x4*)(wq + (16 + lr) * 64 + 48 + lq * 4);
            float ks0 = sc[16 + lq * 4 + 0], ks1 = sc[16 + lq * 4 + 1];
            float ks2 = sc[16 + lq * 4 + 2], ks3 = sc[16 + lq * 4 + 3];
            float kb0 = bi[16 + lq * 4 + 0], kb1 = bi[16 + lq * 4 + 1];
            float kb2 = bi[16 + lq * 4 + 2], kb3 = bi[16 + lq * 4 + 3];
#pragma unroll
            for (int mt = 0; mt < 13; ++mt) {
                const _Float16* xr = xf + (mt * 16 + lr) * 68;
                f32x4 acc = fz;
                acc = MFMA16(ak0, *(const f16x4*)(xr +  0 + lq * 4), acc);
                acc = MFMA16(ak1, *(const f16x4*)(xr + 16 + lq * 4), acc);
                acc = MFMA16(ak2, *(const f16x4*)(xr + 32 + lq * 4), acc);
                acc = MFMA16(ak3, *(const f16x4*)(xr + 48 + lq * 4), acc);
                kf[mt] = mk4(pk(fmaf(acc[0], ks0, kb0), fmaf(acc[1], ks1, kb1)),
                             pk(fmaf(acc[2], ks2, kb2), fmaf(acc[3], ks3, kb3)));
            }
            // V projection: o 32..95
            f16x4 av[16];
            float vs[16], vb[16];
#pragma unroll
            for (int ot = 0; ot < 4; ++ot) {
#pragma unroll
                for (int k4 = 0; k4 < 4; ++k4)
                    av[ot * 4 + k4] = *(const f16x4*)(wq + (32 + ot * 16 + lr) * 64
                                                      + k4 * 16 + lq * 4);
#pragma unroll
                for (int j = 0; j < 4; ++j) {
                    vs[ot * 4 + j] = sc[32 + ot * 16 + lq * 4 + j];
                    vb[ot * 4 + j] = bi[32 + ot * 16 + lq * 4 + j];
                }
            }
#pragma unroll 1
            for (int nt = w; nt < 13; nt += 4) {
                const _Float16* xr = xf + (nt * 16 + lr) * 68;
                f16x4 bx0 = *(const f16x4*)(xr +  0 + lq * 4);
                f16x4 bx1 = *(const f16x4*)(xr + 16 + lq * 4);
                f16x4 bx2 = *(const f16x4*)(xr + 32 + lq * 4);
                f16x4 bx3 = *(const f16x4*)(xr + 48 + lq * 4);
                int m = nt * 16 + lr;
                bool mok = m < NPOS;
#pragma unroll
                for (int ot = 0; ot < 4; ++ot) {
                    f32x4 acc = fz;
                    acc = MFMA16(av[ot * 4 + 0], bx0, acc);
                    acc = MFMA16(av[ot * 4 + 1], bx1, acc);
                    acc = MFMA16(av[ot * 4 + 2], bx2, acc);
                    acc = MFMA16(av[ot * 4 + 3], bx3, acc);
                    if (mok) {
#pragma unroll
                        for (int j = 0; j < 4; ++j)
                            vt[(ot * 16 + lq * 4 + j) * 216 + m] =
                                (_Float16)fmaf(acc[j], vs[ot * 4 + j], vb[ot * 4 + j]);
                    }
                }
            }
            if (t < 192) {  // zero vt cols 196..207 (64 rows * 12 halves)
                int row = t / 3, off = t - (t / 3) * 3;
                *(float2*)(vt + row * 216 + 196 + off * 4) = make_float2(0.f, 0.f);
            }
        }
        __syncthreads();  // B3: qn, vt ready

        // ---- p4: S^T = K^T Q' (MFMA) -> softmax in-reg -> O = V P^T -------
        h2* cb = catI + ((size_t)b * 128 + i * 32) * NPOS;
        const float* xnp = xb + (size_t)(i + 1) * (DV * NPOS);
        const bool more = (i < NH - 1);
#pragma unroll 1
        for (int nt = w; nt < 13; nt += 4) {
            int nn = nt * 16 + lr;
            bool nok = nn < NPOS;
            int rnn = (nn * 4682) >> 16;
            int cnn = nn - rnn * 14;
            f16x4 qb = *(const f16x4*)(qn + nn * 20 + lq * 4);
            f16x4 pf[13];
            float den = 0.f;
#pragma unroll
            for (int mt = 0; mt < 13; ++mt) {
                f32x4 sv = MFMA16(kf[mt], qb, fz);
                float p0, p1, p2, p3;
                {
                    int m0 = mt * 16 + lq * 4;
                    int rm0 = (m0 * 4682) >> 16;       int cm0 = m0 - rm0 * 14;
                    int rm1 = ((m0 + 1) * 4682) >> 16; int cm1 = m0 + 1 - rm1 * 14;
                    int rm2 = ((m0 + 2) * 4682) >> 16; int cm2 = m0 + 2 - rm2 * 14;
                    int rm3 = ((m0 + 3) * 4682) >> 16; int cm3 = m0 + 3 - rm3 * 14;
                    int dr0 = rnn - rm0; dr0 = dr0 < 0 ? -dr0 : dr0;
                    int dr1 = rnn - rm1; dr1 = dr1 < 0 ? -dr1 : dr1;
                    int dr2 = rnn - rm2; dr2 = dr2 < 0 ? -dr2 : dr2;
                    int dr3 = rnn - rm3; dr3 = dr3 < 0 ? -dr3 : dr3;
                    int dc0 = cnn - cm0; dc0 = dc0 < 0 ? -dc0 : dc0;
                    int dc1 = cnn - cm1; dc1 = dc1 < 0 ? -dc1 : dc1;
                    int dc2 = cnn - cm2; dc2 = dc2 < 0 ? -dc2 : dc2;
                    int dc3 = cnn - cm3; dc3 = dc3 < 0 ? -dc3 : dc3;
                    p0 = __expf(fmaf(sv[0], 0.25f, bl[dr0 * 14 + dc0]));
                    p1 = __expf(fmaf(sv[1], 0.25f, bl[dr1 * 14 + dc1]));
                    p2 = __expf(fmaf(sv[2], 0.25f, bl[dr2 * 14 + dc2]));
                    p3 = __expf(fmaf(sv[3], 0.25f, bl[dr3 * 14 + dc3]));
                    if (m0 + 3 >= NPOS) {  // only last m-tile can clip
                        p0 = (m0 + 0 < NPOS) ? p0 : 0.f;
                        p1 = (m0 + 1 < NPOS) ? p1 : 0.f;
                        p2 = (m0 + 2 < NPOS) ? p2 : 0.f;
                        p3 = (m0 + 3 < NPOS) ? p3 : 0.f;
                    }
                }
                den += p0 + p1 + p2 + p3;
                pf[mt] = mk4(pkz(p0, p1), pkz(p2, p3));
            }
            den += __shfl_xor(den, 16, 64);
            den += __shfl_xor(den, 32, 64);
            float inv = 1.f / den;

            f32x4 o0 = fz, o1 = fz, o2 = fz, o3 = fz;
#pragma unroll
            for (int mt = 0; mt < 13; ++mt) {
                const _Float16* vr = vt + mt * 16 + lq * 4;
                o0 = MFMA16(*(const f16x4*)(vr + ( 0 + lr) * 216), pf[mt], o0);
                o1 = MFMA16(*(const f16x4*)(vr + (16 + lr) * 216), pf[mt], o1);
                o2 = MFMA16(*(const f16x4*)(vr + (32 + lr) * 216), pf[mt], o2);
                o3 = MFMA16(*(const f16x4*)(vr + (48 + lr) * 216), pf[mt], o3);
            }
            if (nok) {
                auto epi = [&](f32x4 oa, int dt) {
                    float v0 = oa[0] * inv, v1 = oa[1] * inv;
                    float v2 = oa[2] * inv, v3 = oa[3] * inv;
                    int c2 = dt * 8 + lq * 2;
                    cb[c2 * NPOS + nn]       = pk(fmaxf(v0, 0.f), fmaxf(v1, 0.f));
                    cb[(c2 + 1) * NPOS + nn] = pk(fmaxf(v2, 0.f), fmaxf(v3, 0.f));
                    if (more) {
                        int c0 = dt * 16 + lq * 4;
                        f16x4 fw = mk4(pk(v0 + xnp[(c0 + 0) * NPOS + nn],
                                          v1 + xnp[(c0 + 1) * NPOS + nn]),
                                       pk(v2 + xnp[(c0 + 2) * NPOS + nn],
                                          v3 + xnp[(c0 + 3) * NPOS + nn]));
                        *(f16x4*)(xf + nn * 68 + c0) = fw;
                    }
                };
                epi(o0, 0); epi(o1, 1); epi(o2, 2); epi(o3, 3);
            }
        }
        __syncthreads();  // B4: xf updated for next head
    }
}

// ---------------------------------------------------------------------------
// Kernel 2: proj GEMM via fdot2. Block = (b, 28-col chunk). thread = out chan.
// ---------------------------------------------------------------------------
__global__ __launch_bounds__(256, 4) void cga_proj(
    const h2* __restrict__ catI, const h2* __restrict__ wh2,
    const float* __restrict__ ps, const float* __restrict__ pb,
    float* __restrict__ out)
{
    __shared__ __align__(16) h2 cl[128 * 28];  // 14336 B
    const int t = threadIdx.x;
    const int b = blockIdx.x / 7;
    const int nc = blockIdx.x - b * 7;
    const int n0 = nc * 28;

    const h2* cb = catI + (size_t)b * (128 * NPOS) + n0;
    for (int idx = t; idx < 128 * 7; idx += 256) {
        int c2 = idx / 7;
        int j4 = idx - c2 * 7;
        *(float4*)&cl[c2 * 28 + j4 * 4] = *(const float4*)&cb[c2 * NPOS + j4 * 4];
    }
    __syncthreads();

    float acc[28];
#pragma unroll
    for (int j = 0; j < 28; ++j) acc[j] = 0.f;

    const h2* wcol = wh2 + t;
    h2 wv[8];
#pragma unroll
    for (int j = 0; j < 8; ++j) wv[j] = wcol[j * DIM];

#pragma unroll 1
    for (int c8 = 0; c8 < 16; ++c8) {
        h2 wn[8];
#pragma unroll
        for (int j = 0; j < 8; ++j)
            wn[j] = wcol[(((c8 * 8) + 8 + j) & 127) * DIM];
#pragma unroll
        for (int j = 0; j < 8; ++j) {
            h2 w = wv[j];
            const float4* cf = (const float4*)&cl[(c8 * 8 + j) * 28];
#pragma unroll
            for (int j4 = 0; j4 < 7; ++j4) {
                float4 cv = cf[j4];
                acc[j4 * 4 + 0] = fdot2(w, as_h2(cv.x), acc[j4 * 4 + 0]);
                acc[j4 * 4 + 1] = fdot2(w, as_h2(cv.y), acc[j4 * 4 + 1]);
                acc[j4 * 4 + 2] = fdot2(w, as_h2(cv.z), acc[j4 * 4 + 2]);
                acc[j4 * 4 + 3] = fdot2(w, as_h2(cv.w), acc[j4 * 4 + 3]);
            }
        }
#pragma unroll
        for (int j = 0; j < 8; ++j) wv[j] = wn[j];
    }

    float s = ps[t], bb = pb[t];
    float* ob = out + ((size_t)b * DIM + t) * NPOS + n0;
#pragma unroll
    for (int j = 0; j < 28; ++j) ob[j] = fmaf(acc[j], s, bb);
}

extern "C" void kernel_launch(void* const* d_in, const int* in_sizes, int n_in,
                              void* d_out, int out_size, void* d_ws, size_t ws_size,
                              hipStream_t stream) {
    const float* x      = (const float*)d_in[0];
    const float* qkv_w  = (const float*)d_in[1];
    const float* qkv_s  = (const float*)d_in[2];
    const float* qkv_b  = (const float*)d_in[3];
    const float* dw_w   = (const float*)d_in[4];
    const float* dw_s   = (const float*)d_in[5];
    const float* dw_b   = (const float*)d_in[6];
    const float* proj_w = (const float*)d_in[7];
    const float* proj_s = (const float*)d_in[8];
    const float* proj_b = (const float*)d_in[9];
    const float* ab     = (const float*)d_in[10];
    float* out = (float*)d_out;

    h2* wh2  = (h2*)d_ws;                          // 32768 h2 = 131072 B
    h2* qw2  = (h2*)((char*)d_ws + 131072);        // 12288 h2 = 49152 B
    h2* catI = (h2*)((char*)d_ws + 180224);        // 512*128*196 h2 = 51.4 MB

    cga_prep<<<176, 256, 0, stream>>>(proj_w, qkv_w, wh2, qw2);
    cga_main<<<512, 256, 0, stream>>>(x, qw2, qkv_s, qkv_b,
                                      dw_w, dw_s, dw_b, ab, catI);
    cga_proj<<<512 * 7, 256, 0, stream>>>(catI, wh2, proj_s, proj_b, out);
}